// Round 19
// baseline (455.994 us; speedup 1.0000x reference)
//
#include <hip/hip_runtime.h>
#include <math.h>

#define G_N 50000
#define D_S 3
#define HC 64
#define IN_DIM 256
#define OUT_DIM 40
#define NL 4
#define NNZV 2400000
#define NN (G_N * D_S)          // 150000
#define SUBROWS 250
#define NSB 600                 // NN / SUBROWS
#define CHUNK 9216
#define NBLK_SCAT 261           // ceil(NNZV / CHUNK)
#define SCAT_THR 1024
#define BWIN 5120               // buf2 window per sub
#define PSUB 9216               // padded pcv window per sub
#define W1_ELEMS (192 * IN_DIM)     // 49152
#define RW_ELEMS (NL * HC * HC)     // 16384
#define RPB 48                  // rows per spmm block (16 stalk-triples)

typedef __attribute__((ext_vector_type(8))) short bf16x8;
typedef __attribute__((ext_vector_type(8))) unsigned short u16x8;
typedef __attribute__((ext_vector_type(4))) float f32x4;
typedef __attribute__((ext_vector_type(8))) int i32x8;

__device__ __forceinline__ float elu_f(float v) {
    return v > 0.0f ? v : expm1f(v);
}

__device__ __forceinline__ unsigned short f2bf(float f) {
    unsigned u = __float_as_uint(f);
    return (unsigned short)((u + 0x7FFF + ((u >> 16) & 1)) >> 16);
}

__device__ __forceinline__ float bf2f(unsigned short u) {
    return __uint_as_float((unsigned)u << 16);
}

// ---------------- one-shot: weight conversion + cursor init + gate table
__global__ __launch_bounds__(256) void conv_w_k(const float* __restrict__ w1,
        const float* __restrict__ rw, const float* __restrict__ eps,
        unsigned short* __restrict__ w1b, unsigned short* __restrict__ rwb,
        int* __restrict__ gcur, float* __restrict__ gtab) {
    int i = blockIdx.x * 256 + threadIdx.x;
    if (i < W1_ELEMS) w1b[i] = f2bf(w1[i]);
    if (i < RW_ELEMS) rwb[i] = f2bf(rw[i]);
    if (i < NSB) gcur[i] = i * BWIN;
    if (i < NL * 3) gtab[i] = 1.0f + tanhf(eps[i]);
}

// ---------------- lin1 via MFMA bf16, barrier-free k-loop
__global__ __launch_bounds__(512) void lin1_mfma(const float* __restrict__ x,
        const unsigned short* __restrict__ w1b, const float* __restrict__ b,
        unsigned short* __restrict__ h0b) {
    __shared__ __align__(16) unsigned short Bb[96][264];   // 50.7 KB
    int tid = threadIdx.x;
    int m0 = blockIdx.x * 128;
    int j0 = blockIdx.y * 96;
    int w = tid >> 6, lane = tid & 63;
    int l15 = lane & 15, kg = lane >> 4;

    #pragma unroll
    for (int p = 0; p < 6; ++p) {
        int uid = p * 512 + tid;
        int j = uid >> 5, kq = uid & 31;
        u16x8 v = *(const u16x8*)(w1b + (size_t)(j0 + j) * IN_DIM + kq * 8);
        *(u16x8*)&Bb[j][kq*8] = v;
    }
    __syncthreads();

    int row = m0 + w * 16 + l15;
    const float* xp = x + (size_t)row * IN_DIM + kg * 8;
    bool rowok = (row < G_N);

    f32x4 acc[6];
    #pragma unroll
    for (int nb = 0; nb < 6; ++nb) acc[nb] = (f32x4){0.f, 0.f, 0.f, 0.f};

    #pragma unroll
    for (int kt = 0; kt < 8; ++kt) {
        int k0 = kt * 32;
        ushort4 lo = make_ushort4(0,0,0,0), hi = lo;
        if (rowok) {
            float4 v0 = *(const float4*)(xp + k0);
            float4 v1 = *(const float4*)(xp + k0 + 4);
            lo.x = f2bf(v0.x); lo.y = f2bf(v0.y); lo.z = f2bf(v0.z); lo.w = f2bf(v0.w);
            hi.x = f2bf(v1.x); hi.y = f2bf(v1.y); hi.z = f2bf(v1.z); hi.w = f2bf(v1.w);
        }
        union { ushort4 u4[2]; bf16x8 bv; } af_u;
        af_u.u4[0] = lo; af_u.u4[1] = hi;
        bf16x8 af = af_u.bv;
        #pragma unroll
        for (int nb = 0; nb < 6; ++nb) {
            bf16x8 bfv = *(const bf16x8*)&Bb[nb*16 + l15][k0 + kg*8];
            acc[nb] = __builtin_amdgcn_mfma_f32_16x16x32_bf16(af, bfv, acc[nb], 0, 0, 0);
        }
    }

    #pragma unroll
    for (int nb = 0; nb < 6; ++nb) {
        float bias = b[j0 + nb*16 + l15];
        #pragma unroll
        for (int i = 0; i < 4; ++i) {
            int gr = m0 + w*16 + kg*4 + i;
            if (gr < G_N)
                h0b[(size_t)gr * 192 + j0 + nb*16 + l15] = f2bf(elu_f(acc[nb][i] + bias));
        }
    }
}

// ---------------- left-mix (layer 0 only; later layers fused into spmm epilogue)
__global__ __launch_bounds__(256) void leftmix_k(const unsigned short* __restrict__ h0b,
        const float* __restrict__ lw, unsigned short* __restrict__ amix) {
    int uid = blockIdx.x * 256 + threadIdx.x;
    if (uid >= NN * 8) return;
    int row = uid >> 3, oct = (uid & 7) * 8;
    int g = row / 3, e = row - g * 3;
    const unsigned short* base = h0b + (size_t)g * 3 * HC + oct;
    u16x8 a0 = *(const u16x8*)(base);
    u16x8 a1 = *(const u16x8*)(base + HC);
    u16x8 a2 = *(const u16x8*)(base + 2 * HC);
    float l0 = lw[e*3+0], l1 = lw[e*3+1], l2 = lw[e*3+2];
    u16x8 o;
    #pragma unroll
    for (int j = 0; j < 8; ++j)
        o[j] = f2bf(l0*bf2f(a0[j]) + l1*bf2f(a1[j]) + l2*bf2f(a2[j]));
    *(u16x8*)(amix + (size_t)row * HC + oct) = o;
}

// ---------------- build step 1: partition COO into fixed per-sub windows
__global__ __launch_bounds__(SCAT_THR) void scatterA_k(const int* __restrict__ rows,
        const int* __restrict__ cols, const float* __restrict__ vals,
        int* __restrict__ gcur, long long* __restrict__ buf2) {
    __shared__ int cnt[NSB];
    __shared__ int base[NSB];
    int tid = threadIdx.x;
    if (tid < NSB) cnt[tid] = 0;
    __syncthreads();
    int c0 = blockIdx.x * CHUNK;
    #pragma unroll
    for (int it = 0; it < CHUNK / SCAT_THR; ++it) {
        int i = c0 + it * SCAT_THR + tid;
        if (i < NNZV) atomicAdd(&cnt[rows[i] / SUBROWS], 1);
    }
    __syncthreads();
    if (tid < NSB) {
        int c = cnt[tid];
        if (c) base[tid] = atomicAdd(&gcur[tid], c);
        cnt[tid] = 0;
    }
    __syncthreads();
    #pragma unroll
    for (int it = 0; it < CHUNK / SCAT_THR; ++it) {
        int i = c0 + it * SCAT_THR + tid;
        if (i < NNZV) {
            int r = rows[i];
            int c = __builtin_nontemporal_load(cols + i);
            float v = __builtin_nontemporal_load(vals + i);
            int s = r / SUBROWS;
            int rloc = r - s * SUBROWS;
            int idx = atomicAdd(&cnt[s], 1);
            long long packed = ((long long)__float_as_int(v) << 32)
                             | (unsigned)((rloc << 18) | c);
            buf2[base[s] + idx] = packed;
        }
    }
}

// ---------------- build step 2: per-sub LDS sort -> row-contiguous padded CSR + rs/re
__global__ __launch_bounds__(256) void sortB_k(const long long* __restrict__ buf2,
        const int* __restrict__ gcur, long long* __restrict__ pcv,
        int* __restrict__ rs, int* __restrict__ re) {
    __shared__ long long ent[BWIN];       // 40 KB
    __shared__ int cnt[SUBROWS];
    __shared__ int off[SUBROWS];
    __shared__ int scanbuf[256];
    int s = blockIdx.x;
    int tid = threadIdx.x;
    int bb = s * BWIN;
    int n = gcur[s] - bb;

    for (int i = tid; i < n; i += 256) ent[i] = buf2[bb + i];
    if (tid < SUBROWS) cnt[tid] = 0;
    __syncthreads();
    for (int i = tid; i < n; i += 256) {
        int rl = ((int)ent[i]) >> 18;
        atomicAdd(&cnt[rl], 1);
    }
    __syncthreads();
    int pc = 0;
    {
        int c = (tid < SUBROWS) ? cnt[tid] : 0;
        pc = (c + 15) & ~15;
        scanbuf[tid] = pc;
    }
    __syncthreads();
    for (int o = 1; o < 256; o <<= 1) {
        int x = 0;
        if (tid >= o) x = scanbuf[tid - o];
        __syncthreads();
        if (tid >= o) scanbuf[tid] += x;
        __syncthreads();
    }
    if (tid < SUBROWS) { off[tid] = scanbuf[tid] - pc; cnt[tid] = scanbuf[tid] - pc; }
    __syncthreads();
    long long* outp = pcv + (size_t)s * PSUB;
    for (int i = tid; i < n; i += 256) {
        long long e = ent[i];
        int rl = ((int)e) >> 18;
        int p = atomicAdd(&cnt[rl], 1);
        outp[p] = e;
    }
    __syncthreads();
    if (tid < SUBROWS) {
        int st = off[tid];
        int en = cnt[tid];
        int gend = st + ((en - st + 15) & ~15);
        for (int p = en; p < gend; ++p) outp[p] = 0;
        int gr = s * SUBROWS + tid;
        rs[gr] = s * PSUB + st;
        re[gr] = s * PSUB + gend;
    }
}

// ---------------- fused SpMM + Wr^T (MFMA) + elu + gated residual + next-layer amix
// block = 48 rows (16 stalk-triples): 4 waves x 12 rows gather; 3 row-tiles x MFMA;
// epilogue stashes new h0 in LDS H, then computes amix for layer l+1 (double-buffered).
__global__ __launch_bounds__(256) void spmm_wr_fused(const int* __restrict__ rs,
        const int* __restrict__ re, const long long* __restrict__ pcv,
        const unsigned short* __restrict__ amix_in, const unsigned short* __restrict__ Wrb,
        unsigned short* __restrict__ h0b, const float* __restrict__ gtab, int l,
        const float* __restrict__ lw_next, unsigned short* __restrict__ amix_out,
        int do_amix) {
    __shared__ __align__(16) unsigned short Wl[64][72];
    __shared__ __align__(16) unsigned short S[RPB][72];
    __shared__ __align__(16) unsigned short H[RPB][72];
    int tid = threadIdx.x;
    int wv = tid >> 6, lane = tid & 63;
    int l15 = lane & 15, kg = lane >> 4;
    int r0 = blockIdx.x * RPB;

    #pragma unroll
    for (int p = 0; p < 2; ++p) {
        int uid = p * 256 + tid;
        int j = uid >> 3, kq = uid & 7;
        *(u16x8*)&Wl[j][kq*8] = *(const u16x8*)(Wrb + (size_t)j * HC + kq * 8);
    }

    // gather: wave wv owns rows r0 + wv*12 .. +11
    #pragma unroll
    for (int i = 0; i < 12; ++i) {
        int w = r0 + wv * 12 + i;
        int s = __builtin_amdgcn_readfirstlane(rs[w]);
        int e = __builtin_amdgcn_readfirstlane(re[w]);   // multiple of 16
        float a0 = 0.f, a1 = 0.f, a2 = 0.f, a3 = 0.f;
        for (int cb = s; cb < e; cb += 16) {
            const long long* p = pcv + cb;
            i32x8 q0, q1, q2, q3;
            asm volatile(
                "s_load_dwordx8 %0, %4, 0x0\n\t"
                "s_load_dwordx8 %1, %4, 0x20\n\t"
                "s_load_dwordx8 %2, %4, 0x40\n\t"
                "s_load_dwordx8 %3, %4, 0x60\n\t"
                "s_waitcnt lgkmcnt(0)"
                : "=s"(q0), "=s"(q1), "=s"(q2), "=s"(q3)
                : "s"(p));
            float hv[16];
            #pragma unroll
            for (int u = 0; u < 4; ++u) {
                hv[u]      = bf2f(amix_in[(size_t)(q0[2*u] & 0x3FFFF) * HC + lane]);
                hv[u + 4]  = bf2f(amix_in[(size_t)(q1[2*u] & 0x3FFFF) * HC + lane]);
                hv[u + 8]  = bf2f(amix_in[(size_t)(q2[2*u] & 0x3FFFF) * HC + lane]);
                hv[u + 12] = bf2f(amix_in[(size_t)(q3[2*u] & 0x3FFFF) * HC + lane]);
            }
            #pragma unroll
            for (int u = 0; u < 4; ++u) {
                a0 = fmaf(__int_as_float(q0[2*u+1]), hv[u],      a0);
                a1 = fmaf(__int_as_float(q1[2*u+1]), hv[u + 4],  a1);
                a2 = fmaf(__int_as_float(q2[2*u+1]), hv[u + 8],  a2);
                a3 = fmaf(__int_as_float(q3[2*u+1]), hv[u + 12], a3);
            }
        }
        S[wv*12 + i][lane] = f2bf((a0 + a1) + (a2 + a3));
    }
    __syncthreads();

    // y = S @ Wr^T for 3 row-tiles; wave wv covers cols [wv*16, wv*16+16)
    f32x4 acc4[3];
    #pragma unroll
    for (int t = 0; t < 3; ++t) acc4[t] = (f32x4){0.f, 0.f, 0.f, 0.f};
    #pragma unroll
    for (int t = 0; t < 3; ++t) {
        #pragma unroll
        for (int ks = 0; ks < 2; ++ks) {
            bf16x8 af  = *(const bf16x8*)&S[t*16 + l15][ks*32 + kg*8];
            bf16x8 bfv = *(const bf16x8*)&Wl[wv*16 + l15][ks*32 + kg*8];
            acc4[t] = __builtin_amdgcn_mfma_f32_16x16x32_bf16(af, bfv, acc4[t], 0, 0, 0);
        }
    }

    // epilogue: h0 update (global + LDS H)
    #pragma unroll
    for (int t = 0; t < 3; ++t) {
        #pragma unroll
        for (int i = 0; i < 4; ++i) {
            int row = r0 + t*16 + kg*4 + i;
            int d = row % 3;
            float gate = gtab[l * 3 + d];
            float y = acc4[t][i];
            float hnew = y > 0.0f ? y : expm1f(y);
            size_t idx = (size_t)row * HC + wv*16 + l15;
            float h0v = bf2f(h0b[idx]);
            unsigned short hb = f2bf(gate * h0v - hnew);
            h0b[idx] = hb;
            H[t*16 + kg*4 + i][wv*16 + l15] = hb;
        }
    }

    if (!do_amix) return;
    __syncthreads();
    // amix for next layer: 48 rows x 64 ch = 3072 elems, 12 per thread
    float L[9];
    #pragma unroll
    for (int i = 0; i < 9; ++i) L[i] = lw_next[i];
    #pragma unroll
    for (int p = 0; p < 12; ++p) {
        int uid = p * 256 + tid;
        int rr = uid >> 6, c = uid & 63;
        int gl = rr / 3, e = rr - gl * 3;
        float m = L[e*3+0]*bf2f(H[gl*3+0][c]) + L[e*3+1]*bf2f(H[gl*3+1][c])
                + L[e*3+2]*bf2f(H[gl*3+2][c]);
        amix_out[(size_t)(r0 + rr) * HC + c] = f2bf(m);
    }
}

// ---------------- lin2 (tiled GEMM over bf16 h, N padded 40->64) + fused log_softmax
__global__ __launch_bounds__(256) void lin2_ls_gemm(const unsigned short* __restrict__ h,
        const float* __restrict__ W, const float* __restrict__ b,
        float* __restrict__ out) {
    const int K = 192;
    __shared__ float As[32][65];
    __shared__ float Bs[32][65];
    int tid = threadIdx.x;
    int tx = tid & 15, ty = tid >> 4;
    int m0 = blockIdx.x * 64;

    float acc[4][4] = {};

    for (int k0 = 0; k0 < K; k0 += 32) {
        {
            int r = tid >> 2, kb = (tid & 3) * 8;
            int gr = m0 + r;
            u16x8 v = (u16x8){0,0,0,0,0,0,0,0};
            if (gr < G_N) v = *(const u16x8*)(h + (size_t)gr * K + k0 + kb);
            #pragma unroll
            for (int j = 0; j < 8; ++j) As[kb + j][r] = bf2f(v[j]);
        }
        {
            int kslot = tid & 7, j = tid >> 3;
            #pragma unroll
            for (int pass = 0; pass < 2; ++pass) {
                int jj = j + pass * 32;
                float4 w4 = make_float4(0.f, 0.f, 0.f, 0.f);
                if (jj < OUT_DIM) w4 = *(const float4*)(W + (size_t)jj * K + k0 + kslot * 4);
                Bs[kslot*4+0][jj] = w4.x; Bs[kslot*4+1][jj] = w4.y;
                Bs[kslot*4+2][jj] = w4.z; Bs[kslot*4+3][jj] = w4.w;
            }
        }
        __syncthreads();
        #pragma unroll 8
        for (int k = 0; k < 32; ++k) {
            float4 a4 = *(const float4*)&As[k][ty*4];
            float4 b4 = *(const float4*)&Bs[k][tx*4];
            float av[4] = {a4.x, a4.y, a4.z, a4.w};
            float bv[4] = {b4.x, b4.y, b4.z, b4.w};
            #pragma unroll
            for (int i = 0; i < 4; ++i)
                #pragma unroll
                for (int j = 0; j < 4; ++j)
                    acc[i][j] = fmaf(av[i], bv[j], acc[i][j]);
        }
        __syncthreads();
    }

    bool validc = (tx < 10);
    float bi[4];
    #pragma unroll
    for (int j = 0; j < 4; ++j) bi[j] = validc ? b[tx*4+j] : 0.0f;

    #pragma unroll
    for (int i = 0; i < 4; ++i) {
        int gr = m0 + ty*4 + i;
        float v[4];
        float mymax = -INFINITY;
        #pragma unroll
        for (int j = 0; j < 4; ++j) {
            v[j] = acc[i][j] + bi[j];
            if (validc) mymax = fmaxf(mymax, v[j]);
        }
        #pragma unroll
        for (int off = 1; off < 16; off <<= 1) mymax = fmaxf(mymax, __shfl_xor(mymax, off));
        float s = 0.0f;
        if (validc) {
            #pragma unroll
            for (int j = 0; j < 4; ++j) s += expf(v[j] - mymax);
        }
        #pragma unroll
        for (int off = 1; off < 16; off <<= 1) s += __shfl_xor(s, off);
        float lse = mymax + logf(s);
        if (gr < G_N && validc) {
            float4 o = make_float4(v[0]-lse, v[1]-lse, v[2]-lse, v[3]-lse);
            *(float4*)(out + (size_t)gr * OUT_DIM + tx*4) = o;
        }
    }
}

extern "C" void kernel_launch(void* const* d_in, const int* in_sizes, int n_in,
                              void* d_out, int out_size, void* d_ws, size_t ws_size,
                              hipStream_t stream) {
    const float* x      = (const float*)d_in[0];
    const int*   rows   = (const int*)d_in[1];
    const int*   cols   = (const int*)d_in[2];
    const float* vals   = (const float*)d_in[3];
    const float* lin1_w = (const float*)d_in[4];
    const float* lin1_b = (const float*)d_in[5];
    const float* left_w = (const float*)d_in[6];
    const float* right_w= (const float*)d_in[7];
    const float* eps    = (const float*)d_in[8];
    const float* lin2_w = (const float*)d_in[9];
    const float* lin2_b = (const float*)d_in[10];
    float* out = (float*)d_out;

    size_t bufElems = (size_t)NN * HC;                       // 9.6M
    unsigned short* h0b   = (unsigned short*)d_ws;           // 19.2 MB (bf16 state)
    unsigned short* amixA = h0b + bufElems;                  // 19.2 MB (ping)
    unsigned short* amixB = amixA + bufElems;                // 19.2 MB (pong)
    long long* pcv = (long long*)(amixB + bufElems);         // NSB*PSUB*8 = 44.2 MB
    int* rs   = (int*)(pcv + (size_t)NSB * PSUB);            // 150016
    int* re   = rs + 150016;                                 // 150016
    int* gcur = re + 150016;                                 // NSB (600) + pad to 640
    float* gtab = (float*)(gcur + 640);                      // 12 floats + pad 16
    unsigned short* w1b = (unsigned short*)(gtab + 16);      // 49152 bf16
    unsigned short* rwb = w1b + W1_ELEMS;                    // 16384 bf16

    // buf2 aliases h0b+amixA region (fully consumed by sortB before lin1 writes h0b)
    long long* buf2 = (long long*)d_ws;                      // NSB*BWIN*8 = 24.6 MB

    dim3 b256(256);

    // --- one-shot weight conversion + sub-bucketed build (reused by all 4 layers) ---
    conv_w_k<<<dim3((W1_ELEMS + 255) / 256), b256, 0, stream>>>(
        lin1_w, right_w, eps, w1b, rwb, gcur, gtab);
    scatterA_k<<<dim3(NBLK_SCAT), dim3(SCAT_THR), 0, stream>>>(rows, cols, vals, gcur, buf2);
    sortB_k<<<dim3(NSB), b256, 0, stream>>>(buf2, gcur, pcv, rs, re);

    // --- lin1 -> h0b (MFMA bf16, barrier-free) ---
    lin1_mfma<<<dim3((G_N + 127) / 128, 2), dim3(512), 0, stream>>>(x, w1b, lin1_b, h0b);

    // --- layer 0 amix, then fused layer loop with amix ping-pong ---
    leftmix_k<<<dim3((NN * 8 + 255) / 256), b256, 0, stream>>>(h0b, left_w, amixA);

    unsigned short* abuf[2] = {amixA, amixB};
    for (int l = 0; l < NL; ++l) {
        int do_amix = (l < NL - 1);
        spmm_wr_fused<<<dim3(NN / RPB), b256, 0, stream>>>(
            rs, re, pcv, abuf[l & 1], rwb + l * HC * HC, h0b, gtab, l,
            left_w + (l + 1 < NL ? (l + 1) * 9 : 0), abuf[(l + 1) & 1], do_amix);
    }

    lin2_ls_gemm<<<dim3((G_N + 63) / 64), b256, 0, stream>>>(h0b, lin2_w, lin2_b, out);
}

// Round 20
// 417.791 us; speedup vs baseline: 1.0914x; 1.0914x over previous
//
#include <hip/hip_runtime.h>
#include <math.h>

#define G_N 50000
#define D_S 3
#define HC 64
#define IN_DIM 256
#define OUT_DIM 40
#define NL 4
#define NNZV 2400000
#define NN (G_N * D_S)          // 150000
#define SUBROWS 250
#define NSB 600                 // NN / SUBROWS
#define CHUNK 9216
#define NBLK_SCAT 261           // ceil(NNZV / CHUNK)
#define SCAT_THR 1024
#define BWIN 5120               // buf2 window per sub
#define PSUB 9216               // padded pcv window per sub
#define W1_ELEMS (192 * IN_DIM)     // 49152
#define RW_ELEMS (NL * HC * HC)     // 16384

typedef __attribute__((ext_vector_type(8))) short bf16x8;
typedef __attribute__((ext_vector_type(8))) unsigned short u16x8;
typedef __attribute__((ext_vector_type(4))) float f32x4;
typedef __attribute__((ext_vector_type(8))) int i32x8;

__device__ __forceinline__ float elu_f(float v) {
    return v > 0.0f ? v : expm1f(v);
}

__device__ __forceinline__ unsigned short f2bf(float f) {
    unsigned u = __float_as_uint(f);
    return (unsigned short)((u + 0x7FFF + ((u >> 16) & 1)) >> 16);
}

__device__ __forceinline__ float bf2f(unsigned short u) {
    return __uint_as_float((unsigned)u << 16);
}

// ---------------- one-shot: weight conversion + cursor init + gate table
__global__ __launch_bounds__(256) void conv_w_k(const float* __restrict__ w1,
        const float* __restrict__ rw, const float* __restrict__ eps,
        unsigned short* __restrict__ w1b, unsigned short* __restrict__ rwb,
        int* __restrict__ gcur, float* __restrict__ gtab) {
    int i = blockIdx.x * 256 + threadIdx.x;
    if (i < W1_ELEMS) w1b[i] = f2bf(w1[i]);
    if (i < RW_ELEMS) rwb[i] = f2bf(rw[i]);
    if (i < NSB) gcur[i] = i * BWIN;
    if (i < NL * 3) gtab[i] = 1.0f + tanhf(eps[i]);
}

// ---------------- lin1 via MFMA bf16, barrier-free k-loop
__global__ __launch_bounds__(512) void lin1_mfma(const float* __restrict__ x,
        const unsigned short* __restrict__ w1b, const float* __restrict__ b,
        unsigned short* __restrict__ h0b) {
    __shared__ __align__(16) unsigned short Bb[96][264];   // 50.7 KB
    int tid = threadIdx.x;
    int m0 = blockIdx.x * 128;
    int j0 = blockIdx.y * 96;
    int w = tid >> 6, lane = tid & 63;
    int l15 = lane & 15, kg = lane >> 4;

    #pragma unroll
    for (int p = 0; p < 6; ++p) {
        int uid = p * 512 + tid;
        int j = uid >> 5, kq = uid & 31;
        u16x8 v = *(const u16x8*)(w1b + (size_t)(j0 + j) * IN_DIM + kq * 8);
        *(u16x8*)&Bb[j][kq*8] = v;
    }
    __syncthreads();

    int row = m0 + w * 16 + l15;
    const float* xp = x + (size_t)row * IN_DIM + kg * 8;
    bool rowok = (row < G_N);

    f32x4 acc[6];
    #pragma unroll
    for (int nb = 0; nb < 6; ++nb) acc[nb] = (f32x4){0.f, 0.f, 0.f, 0.f};

    #pragma unroll
    for (int kt = 0; kt < 8; ++kt) {
        int k0 = kt * 32;
        ushort4 lo = make_ushort4(0,0,0,0), hi = lo;
        if (rowok) {
            float4 v0 = *(const float4*)(xp + k0);
            float4 v1 = *(const float4*)(xp + k0 + 4);
            lo.x = f2bf(v0.x); lo.y = f2bf(v0.y); lo.z = f2bf(v0.z); lo.w = f2bf(v0.w);
            hi.x = f2bf(v1.x); hi.y = f2bf(v1.y); hi.z = f2bf(v1.z); hi.w = f2bf(v1.w);
        }
        union { ushort4 u4[2]; bf16x8 bv; } af_u;
        af_u.u4[0] = lo; af_u.u4[1] = hi;
        bf16x8 af = af_u.bv;
        #pragma unroll
        for (int nb = 0; nb < 6; ++nb) {
            bf16x8 bfv = *(const bf16x8*)&Bb[nb*16 + l15][k0 + kg*8];
            acc[nb] = __builtin_amdgcn_mfma_f32_16x16x32_bf16(af, bfv, acc[nb], 0, 0, 0);
        }
    }

    #pragma unroll
    for (int nb = 0; nb < 6; ++nb) {
        float bias = b[j0 + nb*16 + l15];
        #pragma unroll
        for (int i = 0; i < 4; ++i) {
            int gr = m0 + w*16 + kg*4 + i;
            if (gr < G_N)
                h0b[(size_t)gr * 192 + j0 + nb*16 + l15] = f2bf(elu_f(acc[nb][i] + bias));
        }
    }
}

// ---------------- left-mix (per layer)
__global__ __launch_bounds__(256) void leftmix_k(const unsigned short* __restrict__ h0b,
        const float* __restrict__ lw, unsigned short* __restrict__ amix) {
    int uid = blockIdx.x * 256 + threadIdx.x;
    if (uid >= NN * 8) return;
    int row = uid >> 3, oct = (uid & 7) * 8;
    int g = row / 3, e = row - g * 3;
    const unsigned short* base = h0b + (size_t)g * 3 * HC + oct;
    u16x8 a0 = *(const u16x8*)(base);
    u16x8 a1 = *(const u16x8*)(base + HC);
    u16x8 a2 = *(const u16x8*)(base + 2 * HC);
    float l0 = lw[e*3+0], l1 = lw[e*3+1], l2 = lw[e*3+2];
    u16x8 o;
    #pragma unroll
    for (int j = 0; j < 8; ++j)
        o[j] = f2bf(l0*bf2f(a0[j]) + l1*bf2f(a1[j]) + l2*bf2f(a2[j]));
    *(u16x8*)(amix + (size_t)row * HC + oct) = o;
}

// ---------------- build step 1: partition COO into fixed per-sub windows
__global__ __launch_bounds__(SCAT_THR) void scatterA_k(const int* __restrict__ rows,
        const int* __restrict__ cols, const float* __restrict__ vals,
        int* __restrict__ gcur, long long* __restrict__ buf2) {
    __shared__ int cnt[NSB];
    __shared__ int base[NSB];
    int tid = threadIdx.x;
    if (tid < NSB) cnt[tid] = 0;
    __syncthreads();
    int c0 = blockIdx.x * CHUNK;
    #pragma unroll
    for (int it = 0; it < CHUNK / SCAT_THR; ++it) {
        int i = c0 + it * SCAT_THR + tid;
        if (i < NNZV) atomicAdd(&cnt[rows[i] / SUBROWS], 1);
    }
    __syncthreads();
    if (tid < NSB) {
        int c = cnt[tid];
        if (c) base[tid] = atomicAdd(&gcur[tid], c);
        cnt[tid] = 0;
    }
    __syncthreads();
    #pragma unroll
    for (int it = 0; it < CHUNK / SCAT_THR; ++it) {
        int i = c0 + it * SCAT_THR + tid;
        if (i < NNZV) {
            int r = rows[i];
            int c = __builtin_nontemporal_load(cols + i);
            float v = __builtin_nontemporal_load(vals + i);
            int s = r / SUBROWS;
            int rloc = r - s * SUBROWS;
            int idx = atomicAdd(&cnt[s], 1);
            long long packed = ((long long)__float_as_int(v) << 32)
                             | (unsigned)((rloc << 18) | c);
            buf2[base[s] + idx] = packed;
        }
    }
}

// ---------------- build step 2: per-sub LDS sort -> row-contiguous padded CSR + rs/re
__global__ __launch_bounds__(256) void sortB_k(const long long* __restrict__ buf2,
        const int* __restrict__ gcur, long long* __restrict__ pcv,
        int* __restrict__ rs, int* __restrict__ re) {
    __shared__ long long ent[BWIN];       // 40 KB
    __shared__ int cnt[SUBROWS];
    __shared__ int off[SUBROWS];
    __shared__ int scanbuf[256];
    int s = blockIdx.x;
    int tid = threadIdx.x;
    int bb = s * BWIN;
    int n = gcur[s] - bb;

    for (int i = tid; i < n; i += 256) ent[i] = buf2[bb + i];
    if (tid < SUBROWS) cnt[tid] = 0;
    __syncthreads();
    for (int i = tid; i < n; i += 256) {
        int rl = ((int)ent[i]) >> 18;
        atomicAdd(&cnt[rl], 1);
    }
    __syncthreads();
    int pc = 0;
    {
        int c = (tid < SUBROWS) ? cnt[tid] : 0;
        pc = (c + 15) & ~15;
        scanbuf[tid] = pc;
    }
    __syncthreads();
    for (int o = 1; o < 256; o <<= 1) {
        int x = 0;
        if (tid >= o) x = scanbuf[tid - o];
        __syncthreads();
        if (tid >= o) scanbuf[tid] += x;
        __syncthreads();
    }
    if (tid < SUBROWS) { off[tid] = scanbuf[tid] - pc; cnt[tid] = scanbuf[tid] - pc; }
    __syncthreads();
    long long* outp = pcv + (size_t)s * PSUB;
    for (int i = tid; i < n; i += 256) {
        long long e = ent[i];
        int rl = ((int)e) >> 18;
        int p = atomicAdd(&cnt[rl], 1);
        outp[p] = e;
    }
    __syncthreads();
    if (tid < SUBROWS) {
        int st = off[tid];
        int en = cnt[tid];
        int gend = st + ((en - st + 15) & ~15);
        for (int p = en; p < gend; ++p) outp[p] = 0;
        int gr = s * SUBROWS + tid;
        rs[gr] = s * PSUB + st;
        re[gr] = s * PSUB + gend;
    }
}

// ---------------- fused SpMM + Wr^T (MFMA) + elu + gated residual
// pcv read via s_load_dwordx8; gathers use uniform amix base + 32-bit voffset
// ((c<<7) SALU + one v_add with lane*2) -> saddr-form global_load_ushort
__global__ __launch_bounds__(256) void spmm_wr_fused(const int* __restrict__ rs,
        const int* __restrict__ re, const long long* __restrict__ pcv,
        const unsigned short* __restrict__ amix, const unsigned short* __restrict__ Wrb,
        unsigned short* __restrict__ h0b, const float* __restrict__ gtab, int l) {
    __shared__ __align__(16) unsigned short Wl[64][72];
    __shared__ __align__(16) unsigned short S[16][72];
    int tid = threadIdx.x;
    int wv = tid >> 6, lane = tid & 63;
    int l15 = lane & 15, kg = lane >> 4;
    int r0 = blockIdx.x * 16;
    const char* amixb = (const char*)amix;
    unsigned lane2 = (unsigned)lane * 2u;

    #pragma unroll
    for (int p = 0; p < 2; ++p) {
        int uid = p * 256 + tid;
        int j = uid >> 3, kq = uid & 7;
        *(u16x8*)&Wl[j][kq*8] = *(const u16x8*)(Wrb + (size_t)j * HC + kq * 8);
    }

    #pragma unroll
    for (int i = 0; i < 4; ++i) {
        int w = r0 + wv * 4 + i;
        int s = __builtin_amdgcn_readfirstlane(rs[w]);
        int e = __builtin_amdgcn_readfirstlane(re[w]);   // multiple of 16
        float a0 = 0.f, a1 = 0.f, a2 = 0.f, a3 = 0.f;
        for (int cb = s; cb < e; cb += 16) {
            const long long* p = pcv + cb;               // uniform base, 128B-aligned
            i32x8 q0, q1, q2, q3;
            asm volatile(
                "s_load_dwordx8 %0, %4, 0x0\n\t"
                "s_load_dwordx8 %1, %4, 0x20\n\t"
                "s_load_dwordx8 %2, %4, 0x40\n\t"
                "s_load_dwordx8 %3, %4, 0x60\n\t"
                "s_waitcnt lgkmcnt(0)"
                : "=s"(q0), "=s"(q1), "=s"(q2), "=s"(q3)
                : "s"(p));
            float hv[16];
            #pragma unroll
            for (int u = 0; u < 4; ++u) {
                unsigned o0 = (((unsigned)q0[2*u] & 0x3FFFFu) << 7) + lane2;  // SALU shl, 1 v_add
                unsigned o1 = (((unsigned)q1[2*u] & 0x3FFFFu) << 7) + lane2;
                unsigned o2 = (((unsigned)q2[2*u] & 0x3FFFFu) << 7) + lane2;
                unsigned o3 = (((unsigned)q3[2*u] & 0x3FFFFu) << 7) + lane2;
                hv[u]      = bf2f(*(const unsigned short*)(amixb + o0));
                hv[u + 4]  = bf2f(*(const unsigned short*)(amixb + o1));
                hv[u + 8]  = bf2f(*(const unsigned short*)(amixb + o2));
                hv[u + 12] = bf2f(*(const unsigned short*)(amixb + o3));
            }
            #pragma unroll
            for (int u = 0; u < 4; ++u) {
                a0 = fmaf(__int_as_float(q0[2*u+1]), hv[u],      a0);
                a1 = fmaf(__int_as_float(q1[2*u+1]), hv[u + 4],  a1);
                a2 = fmaf(__int_as_float(q2[2*u+1]), hv[u + 8],  a2);
                a3 = fmaf(__int_as_float(q3[2*u+1]), hv[u + 12], a3);
            }
        }
        S[wv*4 + i][lane] = f2bf((a0 + a1) + (a2 + a3));
    }
    __syncthreads();

    f32x4 acc4 = (f32x4){0.f, 0.f, 0.f, 0.f};
    #pragma unroll
    for (int ks = 0; ks < 2; ++ks) {
        bf16x8 af  = *(const bf16x8*)&S[l15][ks*32 + kg*8];
        bf16x8 bfv = *(const bf16x8*)&Wl[wv*16 + l15][ks*32 + kg*8];
        acc4 = __builtin_amdgcn_mfma_f32_16x16x32_bf16(af, bfv, acc4, 0, 0, 0);
    }

    #pragma unroll
    for (int i = 0; i < 4; ++i) {
        int row = r0 + kg*4 + i;
        int d = row % 3;
        float gate = gtab[l * 3 + d];
        float y = acc4[i];
        float hnew = y > 0.0f ? y : expm1f(y);
        size_t idx = (size_t)row * HC + wv*16 + l15;
        float h0v = bf2f(h0b[idx]);
        h0b[idx] = f2bf(gate * h0v - hnew);
    }
}

// ---------------- lin2 (tiled GEMM over bf16 h, N padded 40->64) + fused log_softmax
__global__ __launch_bounds__(256) void lin2_ls_gemm(const unsigned short* __restrict__ h,
        const float* __restrict__ W, const float* __restrict__ b,
        float* __restrict__ out) {
    const int K = 192;
    __shared__ float As[32][65];
    __shared__ float Bs[32][65];
    int tid = threadIdx.x;
    int tx = tid & 15, ty = tid >> 4;
    int m0 = blockIdx.x * 64;

    float acc[4][4] = {};

    for (int k0 = 0; k0 < K; k0 += 32) {
        {
            int r = tid >> 2, kb = (tid & 3) * 8;
            int gr = m0 + r;
            u16x8 v = (u16x8){0,0,0,0,0,0,0,0};
            if (gr < G_N) v = *(const u16x8*)(h + (size_t)gr * K + k0 + kb);
            #pragma unroll
            for (int j = 0; j < 8; ++j) As[kb + j][r] = bf2f(v[j]);
        }
        {
            int kslot = tid & 7, j = tid >> 3;
            #pragma unroll
            for (int pass = 0; pass < 2; ++pass) {
                int jj = j + pass * 32;
                float4 w4 = make_float4(0.f, 0.f, 0.f, 0.f);
                if (jj < OUT_DIM) w4 = *(const float4*)(W + (size_t)jj * K + k0 + kslot * 4);
                Bs[kslot*4+0][jj] = w4.x; Bs[kslot*4+1][jj] = w4.y;
                Bs[kslot*4+2][jj] = w4.z; Bs[kslot*4+3][jj] = w4.w;
            }
        }
        __syncthreads();
        #pragma unroll 8
        for (int k = 0; k < 32; ++k) {
            float4 a4 = *(const float4*)&As[k][ty*4];
            float4 b4 = *(const float4*)&Bs[k][tx*4];
            float av[4] = {a4.x, a4.y, a4.z, a4.w};
            float bv[4] = {b4.x, b4.y, b4.z, b4.w};
            #pragma unroll
            for (int i = 0; i < 4; ++i)
                #pragma unroll
                for (int j = 0; j < 4; ++j)
                    acc[i][j] = fmaf(av[i], bv[j], acc[i][j]);
        }
        __syncthreads();
    }

    bool validc = (tx < 10);
    float bi[4];
    #pragma unroll
    for (int j = 0; j < 4; ++j) bi[j] = validc ? b[tx*4+j] : 0.0f;

    #pragma unroll
    for (int i = 0; i < 4; ++i) {
        int gr = m0 + ty*4 + i;
        float v[4];
        float mymax = -INFINITY;
        #pragma unroll
        for (int j = 0; j < 4; ++j) {
            v[j] = acc[i][j] + bi[j];
            if (validc) mymax = fmaxf(mymax, v[j]);
        }
        #pragma unroll
        for (int off = 1; off < 16; off <<= 1) mymax = fmaxf(mymax, __shfl_xor(mymax, off));
        float s = 0.0f;
        if (validc) {
            #pragma unroll
            for (int j = 0; j < 4; ++j) s += expf(v[j] - mymax);
        }
        #pragma unroll
        for (int off = 1; off < 16; off <<= 1) s += __shfl_xor(s, off);
        float lse = mymax + logf(s);
        if (gr < G_N && validc) {
            float4 o = make_float4(v[0]-lse, v[1]-lse, v[2]-lse, v[3]-lse);
            *(float4*)(out + (size_t)gr * OUT_DIM + tx*4) = o;
        }
    }
}

extern "C" void kernel_launch(void* const* d_in, const int* in_sizes, int n_in,
                              void* d_out, int out_size, void* d_ws, size_t ws_size,
                              hipStream_t stream) {
    const float* x      = (const float*)d_in[0];
    const int*   rows   = (const int*)d_in[1];
    const int*   cols   = (const int*)d_in[2];
    const float* vals   = (const float*)d_in[3];
    const float* lin1_w = (const float*)d_in[4];
    const float* lin1_b = (const float*)d_in[5];
    const float* left_w = (const float*)d_in[6];
    const float* right_w= (const float*)d_in[7];
    const float* eps    = (const float*)d_in[8];
    const float* lin2_w = (const float*)d_in[9];
    const float* lin2_b = (const float*)d_in[10];
    float* out = (float*)d_out;

    size_t bufElems = (size_t)NN * HC;                       // 9.6M
    unsigned short* h0b  = (unsigned short*)d_ws;            // 19.2 MB (bf16 state)
    unsigned short* amix = h0b + bufElems;                   // 19.2 MB (left-mixed)
    long long* pcv = (long long*)(amix + bufElems);          // NSB*PSUB*8 = 44.2 MB
    int* rs   = (int*)(pcv + (size_t)NSB * PSUB);            // 150016
    int* re   = rs + 150016;                                 // 150016
    int* gcur = re + 150016;                                 // NSB (600) + pad to 640
    float* gtab = (float*)(gcur + 640);                      // 12 floats + pad 16
    unsigned short* w1b = (unsigned short*)(gtab + 16);      // 49152 bf16
    unsigned short* rwb = w1b + W1_ELEMS;                    // 16384 bf16

    // buf2 aliases h0b+amix region (fully consumed by sortB before lin1 writes h0b)
    long long* buf2 = (long long*)d_ws;                      // NSB*BWIN*8 = 24.6 MB

    dim3 b256(256);

    // --- one-shot weight conversion + sub-bucketed build (reused by all 4 layers) ---
    conv_w_k<<<dim3((W1_ELEMS + 255) / 256), b256, 0, stream>>>(
        lin1_w, right_w, eps, w1b, rwb, gcur, gtab);
    scatterA_k<<<dim3(NBLK_SCAT), dim3(SCAT_THR), 0, stream>>>(rows, cols, vals, gcur, buf2);
    sortB_k<<<dim3(NSB), b256, 0, stream>>>(buf2, gcur, pcv, rs, re);

    // --- lin1 -> h0b (MFMA bf16, barrier-free) ---
    lin1_mfma<<<dim3((G_N + 127) / 128, 2), dim3(512), 0, stream>>>(x, w1b, lin1_b, h0b);

    for (int l = 0; l < NL; ++l) {
        leftmix_k<<<dim3((NN * 8 + 255) / 256), b256, 0, stream>>>(
            h0b, left_w + l * 9, amix);
        spmm_wr_fused<<<dim3(NN / 16), b256, 0, stream>>>(
            rs, re, pcv, amix, rwb + l * HC * HC, h0b, gtab, l);
    }

    lin2_ls_gemm<<<dim3((G_N + 63) / 64), b256, 0, stream>>>(h0b, lin2_w, lin2_b, out);
}

// Round 21
// 411.196 us; speedup vs baseline: 1.1089x; 1.0160x over previous
//
#include <hip/hip_runtime.h>
#include <math.h>

#define G_N 50000
#define D_S 3
#define HC 64
#define IN_DIM 256
#define OUT_DIM 40
#define NL 4
#define NNZV 2400000
#define NN (G_N * D_S)          // 150000
#define SUBROWS 250
#define NSB 600                 // NN / SUBROWS
#define CHUNK 9216
#define NBLK_SCAT 261           // ceil(NNZV / CHUNK)
#define SCAT_THR 1024
#define BWIN 5120               // buf2 window per sub
#define PSUB 9216               // padded pcv window per sub
#define W1_ELEMS (192 * IN_DIM)     // 49152
#define RW_ELEMS (NL * HC * HC)     // 16384

typedef __attribute__((ext_vector_type(8))) short bf16x8;
typedef __attribute__((ext_vector_type(8))) unsigned short u16x8;
typedef __attribute__((ext_vector_type(4))) float f32x4;
typedef __attribute__((ext_vector_type(8))) int i32x8;

__device__ __forceinline__ float elu_f(float v) {
    return v > 0.0f ? v : expm1f(v);
}

__device__ __forceinline__ unsigned short f2bf(float f) {
    unsigned u = __float_as_uint(f);
    return (unsigned short)((u + 0x7FFF + ((u >> 16) & 1)) >> 16);
}

__device__ __forceinline__ float bf2f(unsigned short u) {
    return __uint_as_float((unsigned)u << 16);
}

// ---------------- one-shot: weight conversion + cursor init + gate table
__global__ __launch_bounds__(256) void conv_w_k(const float* __restrict__ w1,
        const float* __restrict__ rw, const float* __restrict__ eps,
        unsigned short* __restrict__ w1b, unsigned short* __restrict__ rwb,
        int* __restrict__ gcur, float* __restrict__ gtab) {
    int i = blockIdx.x * 256 + threadIdx.x;
    if (i < W1_ELEMS) w1b[i] = f2bf(w1[i]);
    if (i < RW_ELEMS) rwb[i] = f2bf(rw[i]);
    if (i < NSB) gcur[i] = i * BWIN;
    if (i < NL * 3) gtab[i] = 1.0f + tanhf(eps[i]);
}

// ---------------- lin1 via MFMA bf16, barrier-free k-loop
__global__ __launch_bounds__(512) void lin1_mfma(const float* __restrict__ x,
        const unsigned short* __restrict__ w1b, const float* __restrict__ b,
        unsigned short* __restrict__ h0b) {
    __shared__ __align__(16) unsigned short Bb[96][264];   // 50.7 KB
    int tid = threadIdx.x;
    int m0 = blockIdx.x * 128;
    int j0 = blockIdx.y * 96;
    int w = tid >> 6, lane = tid & 63;
    int l15 = lane & 15, kg = lane >> 4;

    #pragma unroll
    for (int p = 0; p < 6; ++p) {
        int uid = p * 512 + tid;
        int j = uid >> 5, kq = uid & 31;
        u16x8 v = *(const u16x8*)(w1b + (size_t)(j0 + j) * IN_DIM + kq * 8);
        *(u16x8*)&Bb[j][kq*8] = v;
    }
    __syncthreads();

    int row = m0 + w * 16 + l15;
    const float* xp = x + (size_t)row * IN_DIM + kg * 8;
    bool rowok = (row < G_N);

    f32x4 acc[6];
    #pragma unroll
    for (int nb = 0; nb < 6; ++nb) acc[nb] = (f32x4){0.f, 0.f, 0.f, 0.f};

    #pragma unroll
    for (int kt = 0; kt < 8; ++kt) {
        int k0 = kt * 32;
        ushort4 lo = make_ushort4(0,0,0,0), hi = lo;
        if (rowok) {
            float4 v0 = *(const float4*)(xp + k0);
            float4 v1 = *(const float4*)(xp + k0 + 4);
            lo.x = f2bf(v0.x); lo.y = f2bf(v0.y); lo.z = f2bf(v0.z); lo.w = f2bf(v0.w);
            hi.x = f2bf(v1.x); hi.y = f2bf(v1.y); hi.z = f2bf(v1.z); hi.w = f2bf(v1.w);
        }
        union { ushort4 u4[2]; bf16x8 bv; } af_u;
        af_u.u4[0] = lo; af_u.u4[1] = hi;
        bf16x8 af = af_u.bv;
        #pragma unroll
        for (int nb = 0; nb < 6; ++nb) {
            bf16x8 bfv = *(const bf16x8*)&Bb[nb*16 + l15][k0 + kg*8];
            acc[nb] = __builtin_amdgcn_mfma_f32_16x16x32_bf16(af, bfv, acc[nb], 0, 0, 0);
        }
    }

    #pragma unroll
    for (int nb = 0; nb < 6; ++nb) {
        float bias = b[j0 + nb*16 + l15];
        #pragma unroll
        for (int i = 0; i < 4; ++i) {
            int gr = m0 + w*16 + kg*4 + i;
            if (gr < G_N)
                h0b[(size_t)gr * 192 + j0 + nb*16 + l15] = f2bf(elu_f(acc[nb][i] + bias));
        }
    }
}

// ---------------- left-mix (per layer)
__global__ __launch_bounds__(256) void leftmix_k(const unsigned short* __restrict__ h0b,
        const float* __restrict__ lw, unsigned short* __restrict__ amix) {
    int uid = blockIdx.x * 256 + threadIdx.x;
    if (uid >= NN * 8) return;
    int row = uid >> 3, oct = (uid & 7) * 8;
    int g = row / 3, e = row - g * 3;
    const unsigned short* base = h0b + (size_t)g * 3 * HC + oct;
    u16x8 a0 = *(const u16x8*)(base);
    u16x8 a1 = *(const u16x8*)(base + HC);
    u16x8 a2 = *(const u16x8*)(base + 2 * HC);
    float l0 = lw[e*3+0], l1 = lw[e*3+1], l2 = lw[e*3+2];
    u16x8 o;
    #pragma unroll
    for (int j = 0; j < 8; ++j)
        o[j] = f2bf(l0*bf2f(a0[j]) + l1*bf2f(a1[j]) + l2*bf2f(a2[j]));
    *(u16x8*)(amix + (size_t)row * HC + oct) = o;
}

// ---------------- build step 1: partition COO into fixed per-sub windows
__global__ __launch_bounds__(SCAT_THR) void scatterA_k(const int* __restrict__ rows,
        const int* __restrict__ cols, const float* __restrict__ vals,
        int* __restrict__ gcur, long long* __restrict__ buf2) {
    __shared__ int cnt[NSB];
    __shared__ int base[NSB];
    int tid = threadIdx.x;
    if (tid < NSB) cnt[tid] = 0;
    __syncthreads();
    int c0 = blockIdx.x * CHUNK;
    #pragma unroll
    for (int it = 0; it < CHUNK / SCAT_THR; ++it) {
        int i = c0 + it * SCAT_THR + tid;
        if (i < NNZV) atomicAdd(&cnt[rows[i] / SUBROWS], 1);
    }
    __syncthreads();
    if (tid < NSB) {
        int c = cnt[tid];
        if (c) base[tid] = atomicAdd(&gcur[tid], c);
        cnt[tid] = 0;
    }
    __syncthreads();
    #pragma unroll
    for (int it = 0; it < CHUNK / SCAT_THR; ++it) {
        int i = c0 + it * SCAT_THR + tid;
        if (i < NNZV) {
            int r = rows[i];
            int c = __builtin_nontemporal_load(cols + i);
            float v = __builtin_nontemporal_load(vals + i);
            int s = r / SUBROWS;
            int rloc = r - s * SUBROWS;
            int idx = atomicAdd(&cnt[s], 1);
            long long packed = ((long long)__float_as_int(v) << 32)
                             | (unsigned)((rloc << 18) | c);
            buf2[base[s] + idx] = packed;
        }
    }
}

// ---------------- build step 2: per-sub LDS sort -> row-contiguous padded CSR + rs/re
__global__ __launch_bounds__(256) void sortB_k(const long long* __restrict__ buf2,
        const int* __restrict__ gcur, long long* __restrict__ pcv,
        int* __restrict__ rs, int* __restrict__ re) {
    __shared__ long long ent[BWIN];       // 40 KB
    __shared__ int cnt[SUBROWS];
    __shared__ int off[SUBROWS];
    __shared__ int scanbuf[256];
    int s = blockIdx.x;
    int tid = threadIdx.x;
    int bb = s * BWIN;
    int n = gcur[s] - bb;

    for (int i = tid; i < n; i += 256) ent[i] = buf2[bb + i];
    if (tid < SUBROWS) cnt[tid] = 0;
    __syncthreads();
    for (int i = tid; i < n; i += 256) {
        int rl = ((int)ent[i]) >> 18;
        atomicAdd(&cnt[rl], 1);
    }
    __syncthreads();
    int pc = 0;
    {
        int c = (tid < SUBROWS) ? cnt[tid] : 0;
        pc = (c + 15) & ~15;
        scanbuf[tid] = pc;
    }
    __syncthreads();
    for (int o = 1; o < 256; o <<= 1) {
        int x = 0;
        if (tid >= o) x = scanbuf[tid - o];
        __syncthreads();
        if (tid >= o) scanbuf[tid] += x;
        __syncthreads();
    }
    if (tid < SUBROWS) { off[tid] = scanbuf[tid] - pc; cnt[tid] = scanbuf[tid] - pc; }
    __syncthreads();
    long long* outp = pcv + (size_t)s * PSUB;
    for (int i = tid; i < n; i += 256) {
        long long e = ent[i];
        int rl = ((int)e) >> 18;
        int p = atomicAdd(&cnt[rl], 1);
        outp[p] = e;
    }
    __syncthreads();
    if (tid < SUBROWS) {
        int st = off[tid];
        int en = cnt[tid];
        int gend = st + ((en - st + 15) & ~15);
        for (int p = en; p < gend; ++p) outp[p] = 0;
        int gr = s * SUBROWS + tid;
        rs[gr] = s * PSUB + st;
        re[gr] = s * PSUB + gend;
    }
}

// ---------------- fused SpMM + Wr^T (MFMA) + elu + gated residual
// rows processed in PAIRS: one merged asm block issues both rows' s_loads before
// a single lgkmcnt wait -> 32 gathers in flight (2x MLP vs serial rows)
__global__ __launch_bounds__(256) void spmm_wr_fused(const int* __restrict__ rs,
        const int* __restrict__ re, const long long* __restrict__ pcv,
        const unsigned short* __restrict__ amix, const unsigned short* __restrict__ Wrb,
        unsigned short* __restrict__ h0b, const float* __restrict__ gtab, int l) {
    __shared__ __align__(16) unsigned short Wl[64][72];
    __shared__ __align__(16) unsigned short S[16][72];
    int tid = threadIdx.x;
    int wv = tid >> 6, lane = tid & 63;
    int l15 = lane & 15, kg = lane >> 4;
    int r0 = blockIdx.x * 16;
    const char* amixb = (const char*)amix;
    unsigned lane2 = (unsigned)lane * 2u;

    #pragma unroll
    for (int p = 0; p < 2; ++p) {
        int uid = p * 256 + tid;
        int j = uid >> 3, kq = uid & 7;
        *(u16x8*)&Wl[j][kq*8] = *(const u16x8*)(Wrb + (size_t)j * HC + kq * 8);
    }

    #pragma unroll
    for (int ip = 0; ip < 2; ++ip) {
        int wA = r0 + wv * 4 + ip * 2;
        int sA = __builtin_amdgcn_readfirstlane(rs[wA]);
        int nA = __builtin_amdgcn_readfirstlane(re[wA]) - sA;
        int sB = __builtin_amdgcn_readfirstlane(rs[wA + 1]);
        int nB = __builtin_amdgcn_readfirstlane(re[wA + 1]) - sB;
        int maxn = nA > nB ? nA : nB;
        float aA0 = 0.f, aA1 = 0.f, aB0 = 0.f, aB1 = 0.f;
        for (int off = 0; off < maxn; off += 16) {
            int offA = off < nA ? off : 0;       // clamp: reads valid mem, result discarded
            int offB = off < nB ? off : 0;
            const long long* pA = pcv + sA + offA;
            const long long* pB = pcv + sB + offB;
            i32x8 qa0, qa1, qa2, qa3, qb0, qb1, qb2, qb3;
            asm volatile(
                "s_load_dwordx8 %0, %8, 0x0\n\t"
                "s_load_dwordx8 %1, %8, 0x20\n\t"
                "s_load_dwordx8 %2, %8, 0x40\n\t"
                "s_load_dwordx8 %3, %8, 0x60\n\t"
                "s_load_dwordx8 %4, %9, 0x0\n\t"
                "s_load_dwordx8 %5, %9, 0x20\n\t"
                "s_load_dwordx8 %6, %9, 0x40\n\t"
                "s_load_dwordx8 %7, %9, 0x60\n\t"
                "s_waitcnt lgkmcnt(0)"
                : "=s"(qa0), "=s"(qa1), "=s"(qa2), "=s"(qa3),
                  "=s"(qb0), "=s"(qb1), "=s"(qb2), "=s"(qb3)
                : "s"(pA), "s"(pB));
            float hvA[16], hvB[16];
            #pragma unroll
            for (int u = 0; u < 4; ++u) {
                unsigned oA0 = (((unsigned)qa0[2*u] & 0x3FFFFu) << 7) + lane2;
                unsigned oA1 = (((unsigned)qa1[2*u] & 0x3FFFFu) << 7) + lane2;
                unsigned oA2 = (((unsigned)qa2[2*u] & 0x3FFFFu) << 7) + lane2;
                unsigned oA3 = (((unsigned)qa3[2*u] & 0x3FFFFu) << 7) + lane2;
                unsigned oB0 = (((unsigned)qb0[2*u] & 0x3FFFFu) << 7) + lane2;
                unsigned oB1 = (((unsigned)qb1[2*u] & 0x3FFFFu) << 7) + lane2;
                unsigned oB2 = (((unsigned)qb2[2*u] & 0x3FFFFu) << 7) + lane2;
                unsigned oB3 = (((unsigned)qb3[2*u] & 0x3FFFFu) << 7) + lane2;
                hvA[u]      = bf2f(*(const unsigned short*)(amixb + oA0));
                hvA[u + 4]  = bf2f(*(const unsigned short*)(amixb + oA1));
                hvA[u + 8]  = bf2f(*(const unsigned short*)(amixb + oA2));
                hvA[u + 12] = bf2f(*(const unsigned short*)(amixb + oA3));
                hvB[u]      = bf2f(*(const unsigned short*)(amixb + oB0));
                hvB[u + 4]  = bf2f(*(const unsigned short*)(amixb + oB1));
                hvB[u + 8]  = bf2f(*(const unsigned short*)(amixb + oB2));
                hvB[u + 12] = bf2f(*(const unsigned short*)(amixb + oB3));
            }
            float tA0 = 0.f, tA1 = 0.f, tB0 = 0.f, tB1 = 0.f;
            #pragma unroll
            for (int u = 0; u < 4; ++u) {
                tA0 = fmaf(__int_as_float(qa0[2*u+1]), hvA[u],      tA0);
                tA1 = fmaf(__int_as_float(qa1[2*u+1]), hvA[u + 4],  tA1);
                tA0 = fmaf(__int_as_float(qa2[2*u+1]), hvA[u + 8],  tA0);
                tA1 = fmaf(__int_as_float(qa3[2*u+1]), hvA[u + 12], tA1);
                tB0 = fmaf(__int_as_float(qb0[2*u+1]), hvB[u],      tB0);
                tB1 = fmaf(__int_as_float(qb1[2*u+1]), hvB[u + 4],  tB1);
                tB0 = fmaf(__int_as_float(qb2[2*u+1]), hvB[u + 8],  tB0);
                tB1 = fmaf(__int_as_float(qb3[2*u+1]), hvB[u + 12], tB1);
            }
            if (off < nA) { aA0 += tA0; aA1 += tA1; }
            if (off < nB) { aB0 += tB0; aB1 += tB1; }
        }
        S[wv*4 + ip*2][lane]     = f2bf(aA0 + aA1);
        S[wv*4 + ip*2 + 1][lane] = f2bf(aB0 + aB1);
    }
    __syncthreads();

    f32x4 acc4 = (f32x4){0.f, 0.f, 0.f, 0.f};
    #pragma unroll
    for (int ks = 0; ks < 2; ++ks) {
        bf16x8 af  = *(const bf16x8*)&S[l15][ks*32 + kg*8];
        bf16x8 bfv = *(const bf16x8*)&Wl[wv*16 + l15][ks*32 + kg*8];
        acc4 = __builtin_amdgcn_mfma_f32_16x16x32_bf16(af, bfv, acc4, 0, 0, 0);
    }

    #pragma unroll
    for (int i = 0; i < 4; ++i) {
        int row = r0 + kg*4 + i;
        int d = row % 3;
        float gate = gtab[l * 3 + d];
        float y = acc4[i];
        float hnew = y > 0.0f ? y : expm1f(y);
        size_t idx = (size_t)row * HC + wv*16 + l15;
        float h0v = bf2f(h0b[idx]);
        h0b[idx] = f2bf(gate * h0v - hnew);
    }
}

// ---------------- lin2 (tiled GEMM over bf16 h, N padded 40->64) + fused log_softmax
__global__ __launch_bounds__(256) void lin2_ls_gemm(const unsigned short* __restrict__ h,
        const float* __restrict__ W, const float* __restrict__ b,
        float* __restrict__ out) {
    const int K = 192;
    __shared__ float As[32][65];
    __shared__ float Bs[32][65];
    int tid = threadIdx.x;
    int tx = tid & 15, ty = tid >> 4;
    int m0 = blockIdx.x * 64;

    float acc[4][4] = {};

    for (int k0 = 0; k0 < K; k0 += 32) {
        {
            int r = tid >> 2, kb = (tid & 3) * 8;
            int gr = m0 + r;
            u16x8 v = (u16x8){0,0,0,0,0,0,0,0};
            if (gr < G_N) v = *(const u16x8*)(h + (size_t)gr * K + k0 + kb);
            #pragma unroll
            for (int j = 0; j < 8; ++j) As[kb + j][r] = bf2f(v[j]);
        }
        {
            int kslot = tid & 7, j = tid >> 3;
            #pragma unroll
            for (int pass = 0; pass < 2; ++pass) {
                int jj = j + pass * 32;
                float4 w4 = make_float4(0.f, 0.f, 0.f, 0.f);
                if (jj < OUT_DIM) w4 = *(const float4*)(W + (size_t)jj * K + k0 + kslot * 4);
                Bs[kslot*4+0][jj] = w4.x; Bs[kslot*4+1][jj] = w4.y;
                Bs[kslot*4+2][jj] = w4.z; Bs[kslot*4+3][jj] = w4.w;
            }
        }
        __syncthreads();
        #pragma unroll 8
        for (int k = 0; k < 32; ++k) {
            float4 a4 = *(const float4*)&As[k][ty*4];
            float4 b4 = *(const float4*)&Bs[k][tx*4];
            float av[4] = {a4.x, a4.y, a4.z, a4.w};
            float bv[4] = {b4.x, b4.y, b4.z, b4.w};
            #pragma unroll
            for (int i = 0; i < 4; ++i)
                #pragma unroll
                for (int j = 0; j < 4; ++j)
                    acc[i][j] = fmaf(av[i], bv[j], acc[i][j]);
        }
        __syncthreads();
    }

    bool validc = (tx < 10);
    float bi[4];
    #pragma unroll
    for (int j = 0; j < 4; ++j) bi[j] = validc ? b[tx*4+j] : 0.0f;

    #pragma unroll
    for (int i = 0; i < 4; ++i) {
        int gr = m0 + ty*4 + i;
        float v[4];
        float mymax = -INFINITY;
        #pragma unroll
        for (int j = 0; j < 4; ++j) {
            v[j] = acc[i][j] + bi[j];
            if (validc) mymax = fmaxf(mymax, v[j]);
        }
        #pragma unroll
        for (int off = 1; off < 16; off <<= 1) mymax = fmaxf(mymax, __shfl_xor(mymax, off));
        float s = 0.0f;
        if (validc) {
            #pragma unroll
            for (int j = 0; j < 4; ++j) s += expf(v[j] - mymax);
        }
        #pragma unroll
        for (int off = 1; off < 16; off <<= 1) s += __shfl_xor(s, off);
        float lse = mymax + logf(s);
        if (gr < G_N && validc) {
            float4 o = make_float4(v[0]-lse, v[1]-lse, v[2]-lse, v[3]-lse);
            *(float4*)(out + (size_t)gr * OUT_DIM + tx*4) = o;
        }
    }
}

extern "C" void kernel_launch(void* const* d_in, const int* in_sizes, int n_in,
                              void* d_out, int out_size, void* d_ws, size_t ws_size,
                              hipStream_t stream) {
    const float* x      = (const float*)d_in[0];
    const int*   rows   = (const int*)d_in[1];
    const int*   cols   = (const int*)d_in[2];
    const float* vals   = (const float*)d_in[3];
    const float* lin1_w = (const float*)d_in[4];
    const float* lin1_b = (const float*)d_in[5];
    const float* left_w = (const float*)d_in[6];
    const float* right_w= (const float*)d_in[7];
    const float* eps    = (const float*)d_in[8];
    const float* lin2_w = (const float*)d_in[9];
    const float* lin2_b = (const float*)d_in[10];
    float* out = (float*)d_out;

    size_t bufElems = (size_t)NN * HC;                       // 9.6M
    unsigned short* h0b  = (unsigned short*)d_ws;            // 19.2 MB (bf16 state)
    unsigned short* amix = h0b + bufElems;                   // 19.2 MB (left-mixed)
    long long* pcv = (long long*)(amix + bufElems);          // NSB*PSUB*8 = 44.2 MB
    int* rs   = (int*)(pcv + (size_t)NSB * PSUB);            // 150016
    int* re   = rs + 150016;                                 // 150016
    int* gcur = re + 150016;                                 // NSB (600) + pad to 640
    float* gtab = (float*)(gcur + 640);                      // 12 floats + pad 16
    unsigned short* w1b = (unsigned short*)(gtab + 16);      // 49152 bf16
    unsigned short* rwb = w1b + W1_ELEMS;                    // 16384 bf16

    // buf2 aliases h0b+amix region (fully consumed by sortB before lin1 writes h0b)
    long long* buf2 = (long long*)d_ws;                      // NSB*BWIN*8 = 24.6 MB

    dim3 b256(256);

    // --- one-shot weight conversion + sub-bucketed build (reused by all 4 layers) ---
    conv_w_k<<<dim3((W1_ELEMS + 255) / 256), b256, 0, stream>>>(
        lin1_w, right_w, eps, w1b, rwb, gcur, gtab);
    scatterA_k<<<dim3(NBLK_SCAT), dim3(SCAT_THR), 0, stream>>>(rows, cols, vals, gcur, buf2);
    sortB_k<<<dim3(NSB), b256, 0, stream>>>(buf2, gcur, pcv, rs, re);

    // --- lin1 -> h0b (MFMA bf16, barrier-free) ---
    lin1_mfma<<<dim3((G_N + 127) / 128, 2), dim3(512), 0, stream>>>(x, w1b, lin1_b, h0b);

    for (int l = 0; l < NL; ++l) {
        leftmix_k<<<dim3((NN * 8 + 255) / 256), b256, 0, stream>>>(
            h0b, left_w + l * 9, amix);
        spmm_wr_fused<<<dim3(NN / 16), b256, 0, stream>>>(
            rs, re, pcv, amix, rwb + l * HC * HC, h0b, gtab, l);
    }

    lin2_ls_gemm<<<dim3((G_N + 63) / 64), b256, 0, stream>>>(h0b, lin2_w, lin2_b, out);
}